// Round 15
// baseline (1266.495 us; speedup 1.0000x reference)
//
#include <hip/hip_runtime.h>
#include <math.h>

typedef unsigned short u16;
typedef __bf16 bf16x8 __attribute__((ext_vector_type(8)));
typedef float f32x4 __attribute__((ext_vector_type(4)));

#define L_   12
#define NTOK 3136
#define MP   3200

__device__ __forceinline__ float b2f(u16 v){ return __builtin_bit_cast(float, (unsigned)v<<16); }
__device__ __forceinline__ u16 f2b(float f){
    unsigned u = __builtin_bit_cast(unsigned, f);
    u += 0x7fffu + ((u>>16)&1u);
    return (u16)(u>>16);
}
__device__ __forceinline__ float wsum(float v){
    #pragma unroll
    for (int o=32;o;o>>=1) v += __shfl_xor(v,o);
    return v;
}
__device__ __forceinline__ void gl_lds16(const void* g, void* l){
    __builtin_amdgcn_global_load_lds(
        (const __attribute__((address_space(1))) void*)g,
        (__attribute__((address_space(3))) void*)l, 16, 0, 0);
}

// 16-col-block z/gate interleave: z col c<768 -> (c>>4)*32+(c&15); gate -> +16
__device__ __host__ __forceinline__ int rho16(int c){
    return (c < 768) ? (((c>>4)<<5) + (c&15)) : ((((c-768)>>4)<<5) + 16 + ((c-768)&15));
}

// ---------------- weight transpose + fp32->bf16 convert -------------------
__global__ __launch_bounds__(256) void k_transpose(const float* __restrict__ src,
                                                   u16* __restrict__ dst, int R, int C){
    __shared__ float t[32][33];
    long long base = (long long)blockIdx.z * R * C;
    int c0 = blockIdx.x<<5, r0 = blockIdx.y<<5;
    int tx = threadIdx.x & 31, ty = threadIdx.x >> 5;
    #pragma unroll
    for (int i=0;i<32;i+=8)
        t[ty+i][tx] = src[base + (long long)(r0+ty+i)*C + c0 + tx];
    __syncthreads();
    #pragma unroll
    for (int i=0;i<32;i+=8)
        dst[base + (long long)(c0+ty+i)*R + r0 + tx] = f2b(t[tx][ty+i]);
}

// pi transpose with 16-block z/gate interleave
__global__ __launch_bounds__(256) void k_transpose_pi(const float* __restrict__ src,
                                                      u16* __restrict__ dst){
    const int R = 384, C = 1536;
    __shared__ float t[32][33];
    long long base = (long long)blockIdx.z * R * C;
    int c0 = blockIdx.x<<5, r0 = blockIdx.y<<5;
    int tx = threadIdx.x & 31, ty = threadIdx.x >> 5;
    #pragma unroll
    for (int i=0;i<32;i+=8)
        t[ty+i][tx] = src[base + (long long)(r0+ty+i)*C + c0 + tx];
    __syncthreads();
    #pragma unroll
    for (int i=0;i<32;i+=8){
        int c = c0 + ty + i;
        dst[base + (long long)rho16(c)*R + r0 + tx] = f2b(t[tx][ty+i]);
    }
}

// interleaved pi bias
__global__ __launch_bounds__(256) void k_bi(const float* __restrict__ pi_b, float* __restrict__ out){
    int idx = blockIdx.x*256 + threadIdx.x;
    if (idx >= 48*1536) return;
    int slab = idx / 1536, c = idx - slab*1536;
    int l = slab >> 2, dir = slab & 3;
    out[(long long)l*6144 + dir*1536 + rho16(c)] = pi_b[idx];
}

// fused: po_bf = bf16(po_w * la_g) AND tvec[z][i] += la_b[z]@po_w[z]
__global__ __launch_bounds__(384) void k_cvt_bw(const float* __restrict__ po_w,
                                                const float* __restrict__ la_g,
                                                const float* __restrict__ la_b,
                                                u16* __restrict__ po_bf,
                                                float* __restrict__ tvec){
    int z = blockIdx.x, chunk = blockIdx.y;   // 48 x 6
    int i = threadIdx.x;                      // 0..383
    const float* pw = po_w + (long long)z*294912;
    u16* ob = po_bf + (long long)z*294912;
    const float* lb = la_b + (long long)z*768;
    const float* lg = la_g + (long long)z*768;
    float s = 0.f;
    int c0 = chunk*128;
    for (int ci=c0; ci<c0+128; ci++){
        float v = pw[(long long)ci*384 + i];
        s = fmaf(lb[ci], v, s);
        ob[(long long)ci*384 + i] = f2b(v * lg[ci]);
    }
    atomicAdd(tvec + (long long)z*384 + i, s);
}

// bw phase 2: fullb[l][i] += sum_{m in chunk} (tvec[z][m]+po_b[z][m])*mg_w[l,dir][m][i]
__global__ __launch_bounds__(384) void k_bw2(const float* __restrict__ tvec,
                                             const float* __restrict__ po_b,
                                             const float* __restrict__ mg_w,
                                             float* __restrict__ fullb){
    int z = blockIdx.x, chunk = blockIdx.y;
    int l = z>>2, dir = z&3;
    int i = threadIdx.x;
    const float* mw = mg_w + (long long)l*589824 + (long long)dir*147456;
    const float* tv = tvec + (long long)z*384;
    const float* pb = po_b + (long long)z*384;
    float s = 0.f;
    int m0 = chunk*64;
    for (int m=m0; m<m0+64; m++) s = fmaf(tv[m]+pb[m], mw[(long long)m*384 + i], s);
    atomicAdd(fullb + (long long)l*384 + i, s);
}

// ---------------- patch extraction ---------------------------------------
__global__ __launch_bounds__(256) void k_patches(const float* __restrict__ x, u16* __restrict__ out){
    int idx = blockIdx.x*256 + threadIdx.x;
    int row = idx / 768, col = idx - row*768;
    float v = 0.f;
    if (row < NTOK){
        int b = row / 196, t = row - b*196;
        int gi = t / 14, gj = t - gi*14;
        int c = col >> 8, rem = col & 255, pi = rem >> 4, pj = rem & 15;
        v = x[((long long)(b*3 + c)*224 + gi*16 + pi)*224 + gj*16 + pj];
    }
    out[idx] = f2b(v);
}

// ---------------- GEMM: C = A(M,K)bf16 @ Bt(N,K)bf16 (+bias) --------------
// Single-buffered LDS -> 5 blocks/CU; per-step vmcnt(0) drain; stage(kt+1)
// overlaps MFMA; cross-block TLP fills drain stalls.
// EPI: 0 bf16, 1 bf16+GELU, 2 f32,
//      3 gated silu*sigmoid (16-block interleave) + partial LN stats -> auxw,
//      4 f32 (acc - mu*G)*rs with in-block stats from aux(pstats), 5 bf16 + col-sums
template<int EPI, int BM, int BN>
__global__ __launch_bounds__(256) void gemm_tn(
    const u16* __restrict__ A, int lda, long long aSh, long long aSl,
    const u16* __restrict__ Bt, int ldb, long long bSh, long long bSl,
    const float* __restrict__ bias, long long biasSh, int splitBias,
    void* __restrict__ Cbase, int ldc, long long cSh, long long cSl,
    int K, int zshift, const float* __restrict__ aux, float* __restrict__ auxw)
{
    constexpr int AI = BM/32;                       // A stage issues per thread
    constexpr int BI = BN/32;                       // B stage issues per thread
    constexpr int NF = (BM==128) ? BN/32 : BN/64;   // B frags per wave
    int z = blockIdx.z;
    int zh = z >> zshift, zl = z - (zh << zshift);
    const u16* Az  = A  + zh*aSh + zl*aSl;
    const u16* Btz = Bt + zh*bSh + zl*bSl;
    bool addb = bias && (!splitBias || zl == 0);
    long long cOff = zh*cSh + zl*cSl;
    int m0 = blockIdx.y*BM, n0 = blockIdx.x*BN;

    __shared__ u16 As[BM*64];
    __shared__ u16 Bs[BN*64];
    __shared__ float2 sln[64];     // EPI==4: per-row (mu, rs)

    int tid = threadIdx.x;
    int lane = tid & 63;
    int w = tid >> 6;
    int wrb = (BM==128) ? (w>>1)*64 : 0;
    int wcb = (BM==128) ? (w&1)*(BN/2) : w*(BN/4);
    int rsub = lane >> 3, csub = lane & 7;
    int scol = ((csub ^ rsub) << 3);
    int kxor = (lane & 7) << 4;

    if (EPI==4 && tid < 64){
        // gather per-row LN stats from pi's 24 sub-chunk partials (row, dir=zl)
        const float2* pp = (const float2*)aux;
        long long base = ((long long)(m0 + tid)*4 + zl)*24;
        float s1 = 0.f, s2 = 0.f;
        #pragma unroll
        for (int c=0;c<24;c++){ float2 v = pp[base + c]; s1 += v.x; s2 += v.y; }
        float mu = s1*(1.f/768.f);
        float rs = rsqrtf(s2*(1.f/768.f) - mu*mu + 1e-5f);
        sln[tid] = make_float2(mu, rs);
    }

    const u16* ga[AI]; const u16* gb[BI]; int loa[AI], lob[BI];
    #pragma unroll
    for (int j=0;j<AI;j++){
        int r = j*32 + w*8 + rsub;
        ga[j] = Az + (long long)(m0 + r)*lda + scol;
        loa[j] = (j*32 + w*8)*64;
    }
    #pragma unroll
    for (int j=0;j<BI;j++){
        int r = j*32 + w*8 + rsub;
        gb[j] = Btz + (long long)(n0 + r)*ldb + scol;
        lob[j] = (j*32 + w*8)*64;
    }

    f32x4 acc[4][NF];
    #pragma unroll
    for (int m=0;m<4;m++)
        #pragma unroll
        for (int n=0;n<NF;n++) acc[m][n] = (f32x4){0.f,0.f,0.f,0.f};

    int nkt = K >> 6;

    auto stage = [&](int ko){
        #pragma unroll
        for (int j=0;j<AI;j++) gl_lds16(ga[j] + ko, &As[loa[j]]);
        #pragma unroll
        for (int j=0;j<BI;j++) gl_lds16(gb[j] + ko, &Bs[lob[j]]);
    };

    stage(0);

    for (int kt=0; kt<nkt; ++kt){
        asm volatile("s_waitcnt vmcnt(0)" ::: "memory");
        __builtin_amdgcn_s_barrier();                 // tile kt staged & visible
        const char* as = (const char*)As;
        const char* bs = (const char*)Bs;
        bf16x8 af[2][4], bfr[2][NF];
        #pragma unroll
        for (int kk=0; kk<2; ++kk){
            int kb = ((kk*32 + ((lane>>4)<<3))*2) ^ kxor;
            #pragma unroll
            for (int m=0;m<4;m++){
                int r = wrb + m*16 + (lane&15);
                af[kk][m] = *reinterpret_cast<const bf16x8*>(as + r*128 + kb);
            }
            #pragma unroll
            for (int n=0;n<NF;n++){
                int r = wcb + n*16 + (lane&15);
                bfr[kk][n] = *reinterpret_cast<const bf16x8*>(bs + r*128 + kb);
            }
        }
        asm volatile("s_waitcnt lgkmcnt(0)" ::: "memory");
        __builtin_amdgcn_sched_barrier(0);
        __builtin_amdgcn_s_barrier();                 // all waves done reading LDS
        if (kt+1 < nkt) stage((kt+1)<<6);             // overwrite under MFMA
        #pragma unroll
        for (int kk=0; kk<2; ++kk)
            #pragma unroll
            for (int m=0;m<4;m++)
                #pragma unroll
                for (int n=0;n<NF;n++)
                    acc[m][n] = __builtin_amdgcn_mfma_f32_16x16x32_bf16(af[kk][m], bfr[kk][n], acc[m][n], 0,0,0);
    }

    int rbase = m0 + wrb;
    int nbase = n0 + wcb;
    if (EPI==3){
        // z/gate in same lane at adjacent frags (16-block interleave): no shuffles.
        // Also emit per-(row,dir,subchunk) partial LN stats (this wave's 32 z-cols).
        int dir = n0/1536;
        int sc  = ((n0 - dir*1536) >> 6) + (wcb >> 6);   // 0..23
        float bzv[NF/2], bgv[NF/2]; int civ[NF/2];
        #pragma unroll
        for (int np2=0; np2<NF/2; ++np2){
            int ncz = nbase + (np2*2)*16 + (lane&15);
            int pz  = ncz - dir*1536;
            civ[np2] = ((pz>>5)<<4) + (pz&15);
            bzv[np2] = addb ? bias[ncz]    : 0.f;
            bgv[np2] = addb ? bias[ncz+16] : 0.f;
        }
        #pragma unroll
        for (int m=0;m<4;m++){
            #pragma unroll
            for (int r4=0;r4<4;r4++){
                int row = rbase + m*16 + ((lane>>4)<<2) + r4;
                float s1 = 0.f, s2 = 0.f;
                #pragma unroll
                for (int np2=0; np2<NF/2; ++np2){
                    float vz = acc[m][np2*2][r4]   + bzv[np2];
                    float vg = acc[m][np2*2+1][r4] + bgv[np2];
                    float gv = vz / ((1.f+__expf(-vz))*(1.f+__expf(-vg)));
                    ((u16*)Cbase)[(long long)row*3072 + dir*768 + civ[np2]] = f2b(gv);
                    s1 += gv; s2 += gv*gv;
                }
                #pragma unroll
                for (int o=1;o<16;o<<=1){ s1 += __shfl_xor(s1,o); s2 += __shfl_xor(s2,o); }
                if ((lane&15)==0)
                    ((float2*)auxw)[((long long)row*4 + dir)*24 + sc] = make_float2(s1, s2);
            }
        }
    } else if (EPI==4){
        // f32 out: (acc - mu*G[n]) * rs ; stats from sln; bias = Gs per-dir slice
        #pragma unroll
        for (int m=0;m<4;m++){
            #pragma unroll
            for (int r4=0;r4<4;r4++){
                int row_l = m*16 + ((lane>>4)<<2) + r4;
                int row = m0 + row_l;
                float mu = sln[row_l].x;
                float rs = sln[row_l].y;
                #pragma unroll
                for (int n=0;n<NF;n++){
                    int ncol = nbase + n*16 + (lane&15);
                    float gsv = bias[(long long)zl*384 + ncol];
                    ((float*)Cbase)[(long long)row*ldc + ncol + cOff] = (acc[m][n][r4] - mu*gsv)*rs;
                }
            }
        }
    } else if (EPI==5){
        // bf16 out + per-(z,row) col-sum atomics (sum of rounded values)
        #pragma unroll
        for (int m=0;m<4;m++){
            #pragma unroll
            for (int r4=0;r4<4;r4++){
                int row = rbase + m*16 + ((lane>>4)<<2) + r4;
                float s = 0.f;
                #pragma unroll
                for (int n=0;n<NF;n++){
                    int ncol = nbase + n*16 + (lane&15);
                    u16 rv = f2b(acc[m][n][r4]);
                    ((u16*)Cbase)[(long long)row*ldc + ncol + cOff] = rv;
                    s += b2f(rv);
                }
                #pragma unroll
                for (int o=1;o<16;o<<=1) s += __shfl_xor(s, o);
                if ((lane&15)==0) atomicAdd(auxw + (long long)z*384 + row, s);
            }
        }
    } else {
        #pragma unroll
        for (int m=0;m<4;m++){
            #pragma unroll
            for (int n=0;n<NF;n++){
                int ncol = nbase + n*16 + (lane&15);
                float bv = addb ? bias[zh*biasSh + ncol] : 0.f;
                #pragma unroll
                for (int r4=0;r4<4;r4++){
                    int row = rbase + m*16 + ((lane>>4)<<2) + r4;
                    float v = acc[m][n][r4] + bv;
                    long long idx = (long long)row*ldc + ncol + cOff;
                    if (EPI==0)      ((u16*)Cbase)[idx] = f2b(v);
                    else if (EPI==1){
                        float gl = 0.5f*v*(1.f + erff(v*0.70710678118f));
                        ((u16*)Cbase)[idx] = f2b(gl);
                    }
                    else             ((float*)Cbase)[idx] = v;
                }
            }
        }
    }
}

// -------- h += sum(parts[np]); LN -> out. MODE 0: bf16 out + update h. MODE 1: f32 out.
template<int MODE>
__global__ __launch_bounds__(256) void k_addln(float* __restrict__ h,
        const float* __restrict__ parts, int np,
        const float* __restrict__ g, const float* __restrict__ b, void* __restrict__ out){
    int row = blockIdx.x*4 + (threadIdx.x>>6);
    int lane = threadIdx.x & 63;
    float* hp = h + (long long)row*384;
    float v[6]; float s = 0.f;
    #pragma unroll
    for (int i=0;i<6;i++){
        int c = lane + i*64;
        float t = hp[c];
        for (int p=0;p<np;p++) t += parts[(long long)p*MP*384 + (long long)row*384 + c];
        v[i] = t; s += t;
    }
    if (MODE==0 && np){
        #pragma unroll
        for (int i=0;i<6;i++) hp[lane + i*64] = v[i];
    }
    float mu = wsum(s)*(1.f/384.f);
    float q = 0.f;
    #pragma unroll
    for (int i=0;i<6;i++){ float d = v[i]-mu; q += d*d; }
    float rs = rsqrtf(wsum(q)*(1.f/384.f) + 1e-5f);
    if (MODE==0){
        u16* op = (u16*)out + (long long)row*384;
        #pragma unroll
        for (int i=0;i<6;i++){ int c = lane + i*64; op[c] = f2b((v[i]-mu)*rs*g[c] + b[c]); }
    } else {
        float* op = (float*)out + (long long)row*384;
        #pragma unroll
        for (int i=0;i<6;i++){ int c = lane + i*64; op[c] = (v[i]-mu)*rs*g[c] + b[c]; }
    }
}

// patch-embed: sum 2 parts -> LN(pe) -> +pos -> h; then LN(n1[0]) -> hn bf16
__global__ __launch_bounds__(256) void k_pe_ln(const float* __restrict__ parts,
        const float* __restrict__ g, const float* __restrict__ b,
        const float* __restrict__ pos, float* __restrict__ h,
        const float* __restrict__ n1g, const float* __restrict__ n1b,
        u16* __restrict__ hn){
    int row = blockIdx.x*4 + (threadIdx.x>>6);
    int lane = threadIdx.x & 63;
    float v[6]; float s = 0.f;
    #pragma unroll
    for (int i=0;i<6;i++){
        int c = lane + i*64;
        float t = parts[(long long)row*384 + c] + parts[(long long)MP*384 + (long long)row*384 + c];
        v[i] = t; s += t;
    }
    float mu = wsum(s)*(1.f/384.f);
    float q = 0.f;
    #pragma unroll
    for (int i=0;i<6;i++){ float d = v[i]-mu; q += d*d; }
    float rs = rsqrtf(wsum(q)*(1.f/384.f) + 1e-5f);
    int t = row % 196;
    const float* pp = pos + (long long)t*384;
    float* op = h + (long long)row*384;
    float hv[6]; float s2 = 0.f;
    #pragma unroll
    for (int i=0;i<6;i++){
        int c = lane + i*64;
        float nv = (v[i]-mu)*rs*g[c] + b[c] + pp[c];
        op[c] = nv; hv[i] = nv; s2 += nv;
    }
    float mu2 = wsum(s2)*(1.f/384.f);
    float q2 = 0.f;
    #pragma unroll
    for (int i=0;i<6;i++){ float d = hv[i]-mu2; q2 += d*d; }
    float rs2 = rsqrtf(wsum(q2)*(1.f/384.f) + 1e-5f);
    u16* hp = hn + (long long)row*384;
    #pragma unroll
    for (int i=0;i<6;i++){ int c = lane + i*64; hp[c] = f2b((hv[i]-mu2)*rs2*n1g[c] + n1b[c]); }
}

// sum 4 parts + fullb -> LN(sn) -> h += -> LN(n2) -> hn bf16
__global__ __launch_bounds__(256) void k_sn_ln(const float* __restrict__ parts,
        const float* __restrict__ fullb, const float* __restrict__ mgb,
        const float* __restrict__ sg, const float* __restrict__ sb,
        float* __restrict__ h,
        const float* __restrict__ n2g, const float* __restrict__ n2b,
        u16* __restrict__ hn2){
    int row = blockIdx.x*4 + (threadIdx.x>>6);
    int lane = threadIdx.x & 63;
    float v[6]; float s = 0.f;
    #pragma unroll
    for (int i=0;i<6;i++){
        int c = lane + i*64;
        long long o = (long long)row*384 + c;
        float t = mgb[c] + fullb[c];
        #pragma unroll
        for (int p=0;p<4;p++) t += parts[(long long)p*MP*384 + o];
        v[i] = t; s += t;
    }
    float mu = wsum(s)*(1.f/384.f);
    float q = 0.f;
    #pragma unroll
    for (int i=0;i<6;i++){ float d = v[i]-mu; q += d*d; }
    float rs = rsqrtf(wsum(q)*(1.f/384.f) + 1e-5f);
    float* hp = h + (long long)row*384;
    float hv[6]; float s2 = 0.f;
    #pragma unroll
    for (int i=0;i<6;i++){
        int c = lane + i*64;
        float nv = hp[c] + (v[i]-mu)*rs*sg[c] + sb[c];
        hp[c] = nv; hv[i] = nv; s2 += nv;
    }
    float mu2 = wsum(s2)*(1.f/384.f);
    float q2 = 0.f;
    #pragma unroll
    for (int i=0;i<6;i++){ float d = hv[i]-mu2; q2 += d*d; }
    float rs2 = rsqrtf(wsum(q2)*(1.f/384.f) + 1e-5f);
    u16* op = hn2 + (long long)row*384;
    #pragma unroll
    for (int i=0;i<6;i++){ int c = lane + i*64; op[c] = f2b((hv[i]-mu2)*rs2*n2g[c] + n2b[c]); }
}

// --------------------------------------------------------------------------
extern "C" void kernel_launch(void* const* d_in, const int* in_sizes, int n_in,
                              void* d_out, int out_size, void* d_ws, size_t ws_size,
                              hipStream_t stream)
{
    const float* x      = (const float*)d_in[0];
    const float* patch_w= (const float*)d_in[1];
    const float* patch_b= (const float*)d_in[2];
    const float* pe_g   = (const float*)d_in[3];
    const float* pe_b   = (const float*)d_in[4];
    const float* pos    = (const float*)d_in[5];
    const float* n1_g   = (const float*)d_in[6];
    const float* n1_b   = (const float*)d_in[7];
    const float* pi_w   = (const float*)d_in[8];
    const float* pi_b   = (const float*)d_in[9];
    const float* po_w   = (const float*)d_in[10];
    const float* po_b   = (const float*)d_in[11];
    const float* la_g   = (const float*)d_in[12];
    const float* la_b   = (const float*)d_in[13];
    const float* mg_w   = (const float*)d_in[14];
    const float* mg_b   = (const float*)d_in[15];
    const float* sn_g   = (const float*)d_in[16];
    const float* sn_b   = (const float*)d_in[17];
    const float* n2_g   = (const float*)d_in[18];
    const float* n2_b   = (const float*)d_in[19];
    const float* m1_w   = (const float*)d_in[20];
    const float* m1_b   = (const float*)d_in[21];
    const float* m2_w   = (const float*)d_in[22];
    const float* m2_b   = (const float*)d_in[23];
    const float* fin_g  = (const float*)d_in[24];
    const float* fin_b  = (const float*)d_in[25];

    char* wptr = (char*)d_ws;
    auto carve = [&](long long elems, int esz)->void*{
        void* p = (void*)wptr;
        wptr += ((elems*(long long)esz + 255)/256)*256;
        return p;
    };

    u16* wt_pi  = (u16*)carve(28311552, 2);   // 48 x (1536,384), 16-block interleaved rows
    u16* wt_mgr = (u16*)carve(7077888, 2);
    u16* wt_m1  = (u16*)carve(7077888, 2);
    u16* wt_m2  = (u16*)carve(7077888, 2);
    u16* wt_pe  = (u16*)carve(294912, 2);
    u16* po_bf  = (u16*)carve(14155776, 2);   // g-folded po_w bf16
    u16* WcT    = (u16*)carve(14155776, 2);   // 12 x (384,3072)
    // zeroed scratch (contiguous -> one memset): Gs, tvec, fullb
    float* Gs   = (float*)carve(48*384, 4);
    float* tvec = (float*)carve(48*384, 4);
    float* fullb= (float*)carve(12*384, 4);
    size_t zbytes = (size_t)((char*)(fullb + 12*384) - (char*)Gs);
    float* pstats=(float*)carve((long long)MP*4*24*2, 4);   // per (row,dir,subchunk) s1,s2
    float* pib_i= (float*)carve(12*6144, 4);
    float* h    = (float*)carve((long long)MP*384, 4);
    float* parts= (float*)carve(4LL*MP*384, 4);
    u16* patches= (u16*)carve((long long)MP*768, 2);
    u16* hn     = (u16*)carve((long long)MP*384, 2);
    u16* gated  = (u16*)carve((long long)MP*3072, 2);
    u16* outs   = (u16*)carve((long long)MP*1536, 2);

    dim3 blk(256);

    // ---- one-time weight prep ----
    hipMemsetAsync(Gs, 0, zbytes, stream);
    k_transpose_pi<<<dim3(48,12,48), blk, 0, stream>>>(pi_w, wt_pi);
    k_bi<<<dim3((48*1536+255)/256), blk, 0, stream>>>(pi_b, pib_i);
    k_transpose<<<dim3(12,12,48), blk, 0, stream>>>(mg_w,   wt_mgr, 384, 384);
    k_transpose<<<dim3(48,12,12), blk, 0, stream>>>(m1_w,   wt_m1, 384, 1536);
    k_transpose<<<dim3(12,48,12), blk, 0, stream>>>(m2_w,   wt_m2, 1536, 384);
    k_transpose<<<dim3(12,24,1),  blk, 0, stream>>>(patch_w,wt_pe, 768, 384);
    k_cvt_bw<<<dim3(48,6), dim3(384), 0, stream>>>(po_w, la_g, la_b, po_bf, tvec);
    k_bw2<<<dim3(48,6), dim3(384), 0, stream>>>(tvec, po_b, mg_w, fullb);
    gemm_tn<5,128,128><<<dim3(6,3,48), blk, 0, stream>>>(
        wt_mgr, 384, 589824LL, 147456LL,
        po_bf,  384, 1179648LL, 294912LL,
        nullptr, 0, 0,
        WcT, 3072, 1179648LL, 768LL, 384, 2, nullptr, Gs);

    // ---- patch embed (split-K=2, BM=64) ----
    k_patches<<<dim3(MP*768/256), blk, 0, stream>>>(x, patches);
    gemm_tn<2,64,128><<<dim3(3,50,2), blk, 0, stream>>>(
        patches, 768, 0, 384,
        wt_pe,   768, 0, 384,
        patch_b, 0, 1,
        parts, 384, 0, (long long)MP*384, 384, 1, nullptr, nullptr);
    k_pe_ln<<<dim3(MP/4), blk, 0, stream>>>(parts, pe_g, pe_b, pos, h, n1_g, n1_b, hn);

    for (int l=0; l<L_; ++l){
        // pi + fused gating + partial LN stats: hn(MP,384)@(384,6144) -> gated(MP,3072)
        gemm_tn<3,128,128><<<dim3(48,25,1), blk, 0, stream>>>(
            hn, 384, 0, 0,
            wt_pi + (long long)l*2359296, 384, 0, 0,
            pib_i + (long long)l*6144, 0, 0,
            gated, 3072, 0, 0, 384, 0, nullptr, pstats);
        // fused LN+po+mg: gated(MP,3072) @ Wc'(3072,384), split-K=4 by dir,
        // in-block stats gather + (acc - mu*G)*rs epilogue
        gemm_tn<4,64,128><<<dim3(3,50,4), blk, 0, stream>>>(
            gated, 3072, 0, 768,
            WcT + (long long)l*1179648, 3072, 0, 768,
            Gs + (long long)l*1536, 0, 0,
            parts, 384, 0, (long long)MP*384, 768, 2, pstats, nullptr);
        k_sn_ln<<<dim3(MP/4), blk, 0, stream>>>(parts,
                                                fullb + (long long)l*384, mg_b + l*384,
                                                sn_g + l*384, sn_b + l*384,
                                                h, n2_g + l*384, n2_b + l*384, hn);
        // MLP up + GELU (BM=64)
        gemm_tn<1,64,128><<<dim3(12,50,1), blk, 0, stream>>>(
            hn, 384, 0, 0,
            wt_m1 + (long long)l*589824, 384, 0, 0,
            m1_b + (long long)l*1536, 0, 0,
            outs, 1536, 0, 0, 384, 0, nullptr, nullptr);
        // MLP down: split-K=4 (600 blocks, 6 steps each)
        gemm_tn<2,64,128><<<dim3(3,50,4), blk, 0, stream>>>(
            outs, 1536, 0, 384,
            wt_m2 + (long long)l*589824, 1536, 0, 384,
            m2_b + l*384, 0, 1,
            parts, 384, 0, (long long)MP*384, 384, 2, nullptr, nullptr);
        if (l < L_-1)
            k_addln<0><<<dim3(MP/4), blk, 0, stream>>>(h, parts, 4,
                n1_g + (l+1)*384, n1_b + (l+1)*384, hn);
        else
            k_addln<1><<<dim3(NTOK/4), blk, 0, stream>>>(h, parts, 4,
                fin_g, fin_b, (float*)d_out);
    }
}

// Round 16
// 1255.638 us; speedup vs baseline: 1.0086x; 1.0086x over previous
//
#include <hip/hip_runtime.h>
#include <math.h>

typedef unsigned short u16;
typedef __bf16 bf16x8 __attribute__((ext_vector_type(8)));
typedef float f32x4 __attribute__((ext_vector_type(4)));

#define L_   12
#define NTOK 3136
#define MP   3200

__device__ __forceinline__ float b2f(u16 v){ return __builtin_bit_cast(float, (unsigned)v<<16); }
__device__ __forceinline__ u16 f2b(float f){
    unsigned u = __builtin_bit_cast(unsigned, f);
    u += 0x7fffu + ((u>>16)&1u);
    return (u16)(u>>16);
}
__device__ __forceinline__ float wsum(float v){
    #pragma unroll
    for (int o=32;o;o>>=1) v += __shfl_xor(v,o);
    return v;
}
__device__ __forceinline__ void gl_lds16(const void* g, void* l){
    __builtin_amdgcn_global_load_lds(
        (const __attribute__((address_space(1))) void*)g,
        (__attribute__((address_space(3))) void*)l, 16, 0, 0);
}

// 16-col-block z/gate interleave: z col c<768 -> (c>>4)*32+(c&15); gate -> +16
__device__ __host__ __forceinline__ int rho16(int c){
    return (c < 768) ? (((c>>4)<<5) + (c&15)) : ((((c-768)>>4)<<5) + 16 + ((c-768)&15));
}

// ---------------- weight transpose + fp32->bf16 convert -------------------
__global__ __launch_bounds__(256) void k_transpose(const float* __restrict__ src,
                                                   u16* __restrict__ dst, int R, int C){
    __shared__ float t[32][33];
    long long base = (long long)blockIdx.z * R * C;
    int c0 = blockIdx.x<<5, r0 = blockIdx.y<<5;
    int tx = threadIdx.x & 31, ty = threadIdx.x >> 5;
    #pragma unroll
    for (int i=0;i<32;i+=8)
        t[ty+i][tx] = src[base + (long long)(r0+ty+i)*C + c0 + tx];
    __syncthreads();
    #pragma unroll
    for (int i=0;i<32;i+=8)
        dst[base + (long long)(c0+ty+i)*R + r0 + tx] = f2b(t[tx][ty+i]);
}

// pi transpose with 16-block z/gate interleave
__global__ __launch_bounds__(256) void k_transpose_pi(const float* __restrict__ src,
                                                      u16* __restrict__ dst){
    const int R = 384, C = 1536;
    __shared__ float t[32][33];
    long long base = (long long)blockIdx.z * R * C;
    int c0 = blockIdx.x<<5, r0 = blockIdx.y<<5;
    int tx = threadIdx.x & 31, ty = threadIdx.x >> 5;
    #pragma unroll
    for (int i=0;i<32;i+=8)
        t[ty+i][tx] = src[base + (long long)(r0+ty+i)*C + c0 + tx];
    __syncthreads();
    #pragma unroll
    for (int i=0;i<32;i+=8){
        int c = c0 + ty + i;
        dst[base + (long long)rho16(c)*R + r0 + tx] = f2b(t[tx][ty+i]);
    }
}

// interleaved pi bias
__global__ __launch_bounds__(256) void k_bi(const float* __restrict__ pi_b, float* __restrict__ out){
    int idx = blockIdx.x*256 + threadIdx.x;
    if (idx >= 48*1536) return;
    int slab = idx / 1536, c = idx - slab*1536;
    int l = slab >> 2, dir = slab & 3;
    out[(long long)l*6144 + dir*1536 + rho16(c)] = pi_b[idx];
}

// fused: po_bf = bf16(po_w * la_g) AND tvec[z][i] += la_b[z]@po_w[z]
__global__ __launch_bounds__(384) void k_cvt_bw(const float* __restrict__ po_w,
                                                const float* __restrict__ la_g,
                                                const float* __restrict__ la_b,
                                                u16* __restrict__ po_bf,
                                                float* __restrict__ tvec){
    int z = blockIdx.x, chunk = blockIdx.y;   // 48 x 6
    int i = threadIdx.x;                      // 0..383
    const float* pw = po_w + (long long)z*294912;
    u16* ob = po_bf + (long long)z*294912;
    const float* lb = la_b + (long long)z*768;
    const float* lg = la_g + (long long)z*768;
    float s = 0.f;
    int c0 = chunk*128;
    for (int ci=c0; ci<c0+128; ci++){
        float v = pw[(long long)ci*384 + i];
        s = fmaf(lb[ci], v, s);
        ob[(long long)ci*384 + i] = f2b(v * lg[ci]);
    }
    atomicAdd(tvec + (long long)z*384 + i, s);
}

// bw phase 2: fullb[l][i] += sum_{m in chunk} (tvec[z][m]+po_b[z][m])*mg_w[l,dir][m][i]
__global__ __launch_bounds__(384) void k_bw2(const float* __restrict__ tvec,
                                             const float* __restrict__ po_b,
                                             const float* __restrict__ mg_w,
                                             float* __restrict__ fullb){
    int z = blockIdx.x, chunk = blockIdx.y;
    int l = z>>2, dir = z&3;
    int i = threadIdx.x;
    const float* mw = mg_w + (long long)l*589824 + (long long)dir*147456;
    const float* tv = tvec + (long long)z*384;
    const float* pb = po_b + (long long)z*384;
    float s = 0.f;
    int m0 = chunk*64;
    for (int m=m0; m<m0+64; m++) s = fmaf(tv[m]+pb[m], mw[(long long)m*384 + i], s);
    atomicAdd(fullb + (long long)l*384 + i, s);
}

// ---------------- patch extraction ---------------------------------------
__global__ __launch_bounds__(256) void k_patches(const float* __restrict__ x, u16* __restrict__ out){
    int idx = blockIdx.x*256 + threadIdx.x;
    int row = idx / 768, col = idx - row*768;
    float v = 0.f;
    if (row < NTOK){
        int b = row / 196, t = row - b*196;
        int gi = t / 14, gj = t - gi*14;
        int c = col >> 8, rem = col & 255, pi = rem >> 4, pj = rem & 15;
        v = x[((long long)(b*3 + c)*224 + gi*16 + pi)*224 + gj*16 + pj];
    }
    out[idx] = f2b(v);
}

// ---------------- GEMM: C = A(M,K)bf16 @ Bt(N,K)bf16 (+bias) --------------
// Single-buffered LDS -> 5 blocks/CU; per-step vmcnt(0) drain; stage(kt+1)
// overlaps MFMA; cross-block TLP fills drain stalls.
// XCD-aware bijective block swizzle (m204): panel-sharing blocks -> same XCD L2.
// EPI: 0 bf16, 1 bf16+GELU, 2 f32,
//      3 gated silu*sigmoid (16-block interleave) + partial LN stats -> auxw,
//      4 f32 (acc - mu*G)*rs with in-block stats from aux(pstats), 5 bf16 + col-sums
template<int EPI, int BM, int BN>
__global__ __launch_bounds__(256) void gemm_tn(
    const u16* __restrict__ A, int lda, long long aSh, long long aSl,
    const u16* __restrict__ Bt, int ldb, long long bSh, long long bSl,
    const float* __restrict__ bias, long long biasSh, int splitBias,
    void* __restrict__ Cbase, int ldc, long long cSh, long long cSl,
    int K, int zshift, const float* __restrict__ aux, float* __restrict__ auxw)
{
    constexpr int AI = BM/32;                       // A stage issues per thread
    constexpr int BI = BN/32;                       // B stage issues per thread
    constexpr int NF = (BM==128) ? BN/32 : BN/64;   // B frags per wave
    int z = blockIdx.z;
    int zh = z >> zshift, zl = z - (zh << zshift);
    const u16* Az  = A  + zh*aSh + zl*aSl;
    const u16* Btz = Bt + zh*bSh + zl*bSl;
    bool addb = bias && (!splitBias || zl == 0);
    long long cOff = zh*cSh + zl*cSl;

    // bijective XCD swizzle of the xy-linear block id (nxy%8 handled via r-adjust)
    int nxy = gridDim.x * gridDim.y;
    int lin = blockIdx.y * gridDim.x + blockIdx.x;
    int q = nxy >> 3, r = nxy & 7;
    int xcd = lin & 7, sidx = lin >> 3;
    int swz = (xcd < r) ? (xcd*(q+1) + sidx) : (r*(q+1) + (xcd-r)*q + sidx);
    int bx = swz % gridDim.x, by = swz / gridDim.x;
    int m0 = by*BM, n0 = bx*BN;

    __shared__ u16 As[BM*64];
    __shared__ u16 Bs[BN*64];
    __shared__ float2 sln[64];     // EPI==4: per-row (mu, rs)

    int tid = threadIdx.x;
    int lane = tid & 63;
    int w = tid >> 6;
    int wrb = (BM==128) ? (w>>1)*64 : 0;
    int wcb = (BM==128) ? (w&1)*(BN/2) : w*(BN/4);
    int rsub = lane >> 3, csub = lane & 7;
    int scol = ((csub ^ rsub) << 3);
    int kxor = (lane & 7) << 4;

    if (EPI==4 && tid < 64){
        // gather per-row LN stats from pi's 24 sub-chunk partials (row, dir=zl)
        const float2* pp = (const float2*)aux;
        long long base = ((long long)(m0 + tid)*4 + zl)*24;
        float s1 = 0.f, s2 = 0.f;
        #pragma unroll
        for (int c=0;c<24;c++){ float2 v = pp[base + c]; s1 += v.x; s2 += v.y; }
        float mu = s1*(1.f/768.f);
        float rs = rsqrtf(s2*(1.f/768.f) - mu*mu + 1e-5f);
        sln[tid] = make_float2(mu, rs);
    }

    const u16* ga[AI]; const u16* gb[BI]; int loa[AI], lob[BI];
    #pragma unroll
    for (int j=0;j<AI;j++){
        int rr = j*32 + w*8 + rsub;
        ga[j] = Az + (long long)(m0 + rr)*lda + scol;
        loa[j] = (j*32 + w*8)*64;
    }
    #pragma unroll
    for (int j=0;j<BI;j++){
        int rr = j*32 + w*8 + rsub;
        gb[j] = Btz + (long long)(n0 + rr)*ldb + scol;
        lob[j] = (j*32 + w*8)*64;
    }

    f32x4 acc[4][NF];
    #pragma unroll
    for (int m=0;m<4;m++)
        #pragma unroll
        for (int n=0;n<NF;n++) acc[m][n] = (f32x4){0.f,0.f,0.f,0.f};

    int nkt = K >> 6;

    auto stage = [&](int ko){
        #pragma unroll
        for (int j=0;j<AI;j++) gl_lds16(ga[j] + ko, &As[loa[j]]);
        #pragma unroll
        for (int j=0;j<BI;j++) gl_lds16(gb[j] + ko, &Bs[lob[j]]);
    };

    stage(0);

    for (int kt=0; kt<nkt; ++kt){
        asm volatile("s_waitcnt vmcnt(0)" ::: "memory");
        __builtin_amdgcn_s_barrier();                 // tile kt staged & visible
        const char* as = (const char*)As;
        const char* bs = (const char*)Bs;
        bf16x8 af[2][4], bfr[2][NF];
        #pragma unroll
        for (int kk=0; kk<2; ++kk){
            int kb = ((kk*32 + ((lane>>4)<<3))*2) ^ kxor;
            #pragma unroll
            for (int m=0;m<4;m++){
                int rr = wrb + m*16 + (lane&15);
                af[kk][m] = *reinterpret_cast<const bf16x8*>(as + rr*128 + kb);
            }
            #pragma unroll
            for (int n=0;n<NF;n++){
                int rr = wcb + n*16 + (lane&15);
                bfr[kk][n] = *reinterpret_cast<const bf16x8*>(bs + rr*128 + kb);
            }
        }
        asm volatile("s_waitcnt lgkmcnt(0)" ::: "memory");
        __builtin_amdgcn_sched_barrier(0);
        __builtin_amdgcn_s_barrier();                 // all waves done reading LDS
        if (kt+1 < nkt) stage((kt+1)<<6);             // overwrite under MFMA
        #pragma unroll
        for (int kk=0; kk<2; ++kk)
            #pragma unroll
            for (int m=0;m<4;m++)
                #pragma unroll
                for (int n=0;n<NF;n++)
                    acc[m][n] = __builtin_amdgcn_mfma_f32_16x16x32_bf16(af[kk][m], bfr[kk][n], acc[m][n], 0,0,0);
    }

    int rbase = m0 + wrb;
    int nbase = n0 + wcb;
    if (EPI==3){
        // z/gate in same lane at adjacent frags (16-block interleave): no shuffles.
        // Also emit per-(row,dir,subchunk) partial LN stats (this wave's 32 z-cols).
        int dir = n0/1536;
        int sc  = ((n0 - dir*1536) >> 6) + (wcb >> 6);   // 0..23
        float bzv[NF/2], bgv[NF/2]; int civ[NF/2];
        #pragma unroll
        for (int np2=0; np2<NF/2; ++np2){
            int ncz = nbase + (np2*2)*16 + (lane&15);
            int pz  = ncz - dir*1536;
            civ[np2] = ((pz>>5)<<4) + (pz&15);
            bzv[np2] = addb ? bias[ncz]    : 0.f;
            bgv[np2] = addb ? bias[ncz+16] : 0.f;
        }
        #pragma unroll
        for (int m=0;m<4;m++){
            #pragma unroll
            for (int r4=0;r4<4;r4++){
                int row = rbase + m*16 + ((lane>>4)<<2) + r4;
                float s1 = 0.f, s2 = 0.f;
                #pragma unroll
                for (int np2=0; np2<NF/2; ++np2){
                    float vz = acc[m][np2*2][r4]   + bzv[np2];
                    float vg = acc[m][np2*2+1][r4] + bgv[np2];
                    float gv = vz / ((1.f+__expf(-vz))*(1.f+__expf(-vg)));
                    ((u16*)Cbase)[(long long)row*3072 + dir*768 + civ[np2]] = f2b(gv);
                    s1 += gv; s2 += gv*gv;
                }
                #pragma unroll
                for (int o=1;o<16;o<<=1){ s1 += __shfl_xor(s1,o); s2 += __shfl_xor(s2,o); }
                if ((lane&15)==0)
                    ((float2*)auxw)[((long long)row*4 + dir)*24 + sc] = make_float2(s1, s2);
            }
        }
    } else if (EPI==4){
        // f32 out: (acc - mu*G[n]) * rs ; stats from sln; bias = Gs per-dir slice
        #pragma unroll
        for (int m=0;m<4;m++){
            #pragma unroll
            for (int r4=0;r4<4;r4++){
                int row_l = m*16 + ((lane>>4)<<2) + r4;
                int row = m0 + row_l;
                float mu = sln[row_l].x;
                float rs = sln[row_l].y;
                #pragma unroll
                for (int n=0;n<NF;n++){
                    int ncol = nbase + n*16 + (lane&15);
                    float gsv = bias[(long long)zl*384 + ncol];
                    ((float*)Cbase)[(long long)row*ldc + ncol + cOff] = (acc[m][n][r4] - mu*gsv)*rs;
                }
            }
        }
    } else if (EPI==5){
        // bf16 out + per-(z,row) col-sum atomics (sum of rounded values)
        #pragma unroll
        for (int m=0;m<4;m++){
            #pragma unroll
            for (int r4=0;r4<4;r4++){
                int row = rbase + m*16 + ((lane>>4)<<2) + r4;
                float s = 0.f;
                #pragma unroll
                for (int n=0;n<NF;n++){
                    int ncol = nbase + n*16 + (lane&15);
                    u16 rv = f2b(acc[m][n][r4]);
                    ((u16*)Cbase)[(long long)row*ldc + ncol + cOff] = rv;
                    s += b2f(rv);
                }
                #pragma unroll
                for (int o=1;o<16;o<<=1) s += __shfl_xor(s, o);
                if ((lane&15)==0) atomicAdd(auxw + (long long)z*384 + row, s);
            }
        }
    } else {
        #pragma unroll
        for (int m=0;m<4;m++){
            #pragma unroll
            for (int n=0;n<NF;n++){
                int ncol = nbase + n*16 + (lane&15);
                float bv = addb ? bias[zh*biasSh + ncol] : 0.f;
                #pragma unroll
                for (int r4=0;r4<4;r4++){
                    int row = rbase + m*16 + ((lane>>4)<<2) + r4;
                    float v = acc[m][n][r4] + bv;
                    long long idx = (long long)row*ldc + ncol + cOff;
                    if (EPI==0)      ((u16*)Cbase)[idx] = f2b(v);
                    else if (EPI==1){
                        float gl = 0.5f*v*(1.f + erff(v*0.70710678118f));
                        ((u16*)Cbase)[idx] = f2b(gl);
                    }
                    else             ((float*)Cbase)[idx] = v;
                }
            }
        }
    }
}

// -------- h += sum(parts[np]); LN -> out. MODE 0: bf16 out + update h. MODE 1: f32 out.
template<int MODE>
__global__ __launch_bounds__(256) void k_addln(float* __restrict__ h,
        const float* __restrict__ parts, int np,
        const float* __restrict__ g, const float* __restrict__ b, void* __restrict__ out){
    int row = blockIdx.x*4 + (threadIdx.x>>6);
    int lane = threadIdx.x & 63;
    float* hp = h + (long long)row*384;
    float v[6]; float s = 0.f;
    #pragma unroll
    for (int i=0;i<6;i++){
        int c = lane + i*64;
        float t = hp[c];
        for (int p=0;p<np;p++) t += parts[(long long)p*MP*384 + (long long)row*384 + c];
        v[i] = t; s += t;
    }
    if (MODE==0 && np){
        #pragma unroll
        for (int i=0;i<6;i++) hp[lane + i*64] = v[i];
    }
    float mu = wsum(s)*(1.f/384.f);
    float q = 0.f;
    #pragma unroll
    for (int i=0;i<6;i++){ float d = v[i]-mu; q += d*d; }
    float rs = rsqrtf(wsum(q)*(1.f/384.f) + 1e-5f);
    if (MODE==0){
        u16* op = (u16*)out + (long long)row*384;
        #pragma unroll
        for (int i=0;i<6;i++){ int c = lane + i*64; op[c] = f2b((v[i]-mu)*rs*g[c] + b[c]); }
    } else {
        float* op = (float*)out + (long long)row*384;
        #pragma unroll
        for (int i=0;i<6;i++){ int c = lane + i*64; op[c] = (v[i]-mu)*rs*g[c] + b[c]; }
    }
}

// patch-embed: sum 2 parts -> LN(pe) -> +pos -> h; then LN(n1[0]) -> hn bf16
__global__ __launch_bounds__(256) void k_pe_ln(const float* __restrict__ parts,
        const float* __restrict__ g, const float* __restrict__ b,
        const float* __restrict__ pos, float* __restrict__ h,
        const float* __restrict__ n1g, const float* __restrict__ n1b,
        u16* __restrict__ hn){
    int row = blockIdx.x*4 + (threadIdx.x>>6);
    int lane = threadIdx.x & 63;
    float v[6]; float s = 0.f;
    #pragma unroll
    for (int i=0;i<6;i++){
        int c = lane + i*64;
        float t = parts[(long long)row*384 + c] + parts[(long long)MP*384 + (long long)row*384 + c];
        v[i] = t; s += t;
    }
    float mu = wsum(s)*(1.f/384.f);
    float q = 0.f;
    #pragma unroll
    for (int i=0;i<6;i++){ float d = v[i]-mu; q += d*d; }
    float rs = rsqrtf(wsum(q)*(1.f/384.f) + 1e-5f);
    int t = row % 196;
    const float* pp = pos + (long long)t*384;
    float* op = h + (long long)row*384;
    float hv[6]; float s2 = 0.f;
    #pragma unroll
    for (int i=0;i<6;i++){
        int c = lane + i*64;
        float nv = (v[i]-mu)*rs*g[c] + b[c] + pp[c];
        op[c] = nv; hv[i] = nv; s2 += nv;
    }
    float mu2 = wsum(s2)*(1.f/384.f);
    float q2 = 0.f;
    #pragma unroll
    for (int i=0;i<6;i++){ float d = hv[i]-mu2; q2 += d*d; }
    float rs2 = rsqrtf(wsum(q2)*(1.f/384.f) + 1e-5f);
    u16* hp = hn + (long long)row*384;
    #pragma unroll
    for (int i=0;i<6;i++){ int c = lane + i*64; hp[c] = f2b((hv[i]-mu2)*rs2*n1g[c] + n1b[c]); }
}

// sum 4 parts + fullb -> LN(sn) -> h += -> LN(n2) -> hn bf16
__global__ __launch_bounds__(256) void k_sn_ln(const float* __restrict__ parts,
        const float* __restrict__ fullb, const float* __restrict__ mgb,
        const float* __restrict__ sg, const float* __restrict__ sb,
        float* __restrict__ h,
        const float* __restrict__ n2g, const float* __restrict__ n2b,
        u16* __restrict__ hn2){
    int row = blockIdx.x*4 + (threadIdx.x>>6);
    int lane = threadIdx.x & 63;
    float v[6]; float s = 0.f;
    #pragma unroll
    for (int i=0;i<6;i++){
        int c = lane + i*64;
        long long o = (long long)row*384 + c;
        float t = mgb[c] + fullb[c];
        #pragma unroll
        for (int p=0;p<4;p++) t += parts[(long long)p*MP*384 + o];
        v[i] = t; s += t;
    }
    float mu = wsum(s)*(1.f/384.f);
    float q = 0.f;
    #pragma unroll
    for (int i=0;i<6;i++){ float d = v[i]-mu; q += d*d; }
    float rs = rsqrtf(wsum(q)*(1.f/384.f) + 1e-5f);
    float* hp = h + (long long)row*384;
    float hv[6]; float s2 = 0.f;
    #pragma unroll
    for (int i=0;i<6;i++){
        int c = lane + i*64;
        float nv = hp[c] + (v[i]-mu)*rs*sg[c] + sb[c];
        hp[c] = nv; hv[i] = nv; s2 += nv;
    }
    float mu2 = wsum(s2)*(1.f/384.f);
    float q2 = 0.f;
    #pragma unroll
    for (int i=0;i<6;i++){ float d = hv[i]-mu2; q2 += d*d; }
    float rs2 = rsqrtf(wsum(q2)*(1.f/384.f) + 1e-5f);
    u16* op = hn2 + (long long)row*384;
    #pragma unroll
    for (int i=0;i<6;i++){ int c = lane + i*64; op[c] = f2b((hv[i]-mu2)*rs2*n2g[c] + n2b[c]); }
}

// --------------------------------------------------------------------------
extern "C" void kernel_launch(void* const* d_in, const int* in_sizes, int n_in,
                              void* d_out, int out_size, void* d_ws, size_t ws_size,
                              hipStream_t stream)
{
    const float* x      = (const float*)d_in[0];
    const float* patch_w= (const float*)d_in[1];
    const float* patch_b= (const float*)d_in[2];
    const float* pe_g   = (const float*)d_in[3];
    const float* pe_b   = (const float*)d_in[4];
    const float* pos    = (const float*)d_in[5];
    const float* n1_g   = (const float*)d_in[6];
    const float* n1_b   = (const float*)d_in[7];
    const float* pi_w   = (const float*)d_in[8];
    const float* pi_b   = (const float*)d_in[9];
    const float* po_w   = (const float*)d_in[10];
    const float* po_b   = (const float*)d_in[11];
    const float* la_g   = (const float*)d_in[12];
    const float* la_b   = (const float*)d_in[13];
    const float* mg_w   = (const float*)d_in[14];
    const float* mg_b   = (const float*)d_in[15];
    const float* sn_g   = (const float*)d_in[16];
    const float* sn_b   = (const float*)d_in[17];
    const float* n2_g   = (const float*)d_in[18];
    const float* n2_b   = (const float*)d_in[19];
    const float* m1_w   = (const float*)d_in[20];
    const float* m1_b   = (const float*)d_in[21];
    const float* m2_w   = (const float*)d_in[22];
    const float* m2_b   = (const float*)d_in[23];
    const float* fin_g  = (const float*)d_in[24];
    const float* fin_b  = (const float*)d_in[25];

    char* wptr = (char*)d_ws;
    auto carve = [&](long long elems, int esz)->void*{
        void* p = (void*)wptr;
        wptr += ((elems*(long long)esz + 255)/256)*256;
        return p;
    };

    u16* wt_pi  = (u16*)carve(28311552, 2);   // 48 x (1536,384), 16-block interleaved rows
    u16* wt_mgr = (u16*)carve(7077888, 2);
    u16* wt_m1  = (u16*)carve(7077888, 2);
    u16* wt_m2  = (u16*)carve(7077888, 2);
    u16* wt_pe  = (u16*)carve(294912, 2);
    u16* po_bf  = (u16*)carve(14155776, 2);   // g-folded po_w bf16
    u16* WcT    = (u16*)carve(14155776, 2);   // 12 x (384,3072)
    // zeroed scratch (contiguous -> one memset): Gs, tvec, fullb
    float* Gs   = (float*)carve(48*384, 4);
    float* tvec = (float*)carve(48*384, 4);
    float* fullb= (float*)carve(12*384, 4);
    size_t zbytes = (size_t)((char*)(fullb + 12*384) - (char*)Gs);
    float* pstats=(float*)carve((long long)MP*4*24*2, 4);   // per (row,dir,subchunk) s1,s2
    float* pib_i= (float*)carve(12*6144, 4);
    float* h    = (float*)carve((long long)MP*384, 4);
    float* parts= (float*)carve(4LL*MP*384, 4);
    u16* patches= (u16*)carve((long long)MP*768, 2);
    u16* hn     = (u16*)carve((long long)MP*384, 2);
    u16* gated  = (u16*)carve((long long)MP*3072, 2);
    u16* outs   = (u16*)carve((long long)MP*1536, 2);

    dim3 blk(256);

    // ---- one-time weight prep ----
    hipMemsetAsync(Gs, 0, zbytes, stream);
    k_transpose_pi<<<dim3(48,12,48), blk, 0, stream>>>(pi_w, wt_pi);
    k_bi<<<dim3((48*1536+255)/256), blk, 0, stream>>>(pi_b, pib_i);
    k_transpose<<<dim3(12,12,48), blk, 0, stream>>>(mg_w,   wt_mgr, 384, 384);
    k_transpose<<<dim3(48,12,12), blk, 0, stream>>>(m1_w,   wt_m1, 384, 1536);
    k_transpose<<<dim3(12,48,12), blk, 0, stream>>>(m2_w,   wt_m2, 1536, 384);
    k_transpose<<<dim3(12,24,1),  blk, 0, stream>>>(patch_w,wt_pe, 768, 384);
    k_cvt_bw<<<dim3(48,6), dim3(384), 0, stream>>>(po_w, la_g, la_b, po_bf, tvec);
    k_bw2<<<dim3(48,6), dim3(384), 0, stream>>>(tvec, po_b, mg_w, fullb);
    gemm_tn<5,128,128><<<dim3(6,3,48), blk, 0, stream>>>(
        wt_mgr, 384, 589824LL, 147456LL,
        po_bf,  384, 1179648LL, 294912LL,
        nullptr, 0, 0,
        WcT, 3072, 1179648LL, 768LL, 384, 2, nullptr, Gs);

    // ---- patch embed (split-K=2, BM=64) ----
    k_patches<<<dim3(MP*768/256), blk, 0, stream>>>(x, patches);
    gemm_tn<2,64,128><<<dim3(3,50,2), blk, 0, stream>>>(
        patches, 768, 0, 384,
        wt_pe,   768, 0, 384,
        patch_b, 0, 1,
        parts, 384, 0, (long long)MP*384, 384, 1, nullptr, nullptr);
    k_pe_ln<<<dim3(MP/4), blk, 0, stream>>>(parts, pe_g, pe_b, pos, h, n1_g, n1_b, hn);

    for (int l=0; l<L_; ++l){
        // pi + fused gating + partial LN stats: hn(MP,384)@(384,6144) -> gated(MP,3072)
        gemm_tn<3,128,128><<<dim3(48,25,1), blk, 0, stream>>>(
            hn, 384, 0, 0,
            wt_pi + (long long)l*2359296, 384, 0, 0,
            pib_i + (long long)l*6144, 0, 0,
            gated, 3072, 0, 0, 384, 0, nullptr, pstats);
        // fused LN+po+mg: gated(MP,3072) @ Wc'(3072,384), split-K=4 by dir,
        // in-block stats gather + (acc - mu*G)*rs epilogue
        gemm_tn<4,64,128><<<dim3(3,50,4), blk, 0, stream>>>(
            gated, 3072, 0, 768,
            WcT + (long long)l*1179648, 3072, 0, 768,
            Gs + (long long)l*1536, 0, 0,
            parts, 384, 0, (long long)MP*384, 768, 2, pstats, nullptr);
        k_sn_ln<<<dim3(MP/4), blk, 0, stream>>>(parts,
                                                fullb + (long long)l*384, mg_b + l*384,
                                                sn_g + l*384, sn_b + l*384,
                                                h, n2_g + l*384, n2_b + l*384, hn);
        // MLP up + GELU (BM=64)
        gemm_tn<1,64,128><<<dim3(12,50,1), blk, 0, stream>>>(
            hn, 384, 0, 0,
            wt_m1 + (long long)l*589824, 384, 0, 0,
            m1_b + (long long)l*1536, 0, 0,
            outs, 1536, 0, 0, 384, 0, nullptr, nullptr);
        // MLP down: split-K=2 (BM=64, 12 K-steps)
        gemm_tn<2,64,128><<<dim3(3,50,2), blk, 0, stream>>>(
            outs, 1536, 0, 768,
            wt_m2 + (long long)l*589824, 1536, 0, 768,
            m2_b + l*384, 0, 1,
            parts, 384, 0, (long long)MP*384, 768, 1, nullptr, nullptr);
        if (l < L_-1)
            k_addln<0><<<dim3(MP/4), blk, 0, stream>>>(h, parts, 2,
                n1_g + (l+1)*384, n1_b + (l+1)*384, hn);
        else
            k_addln<1><<<dim3(NTOK/4), blk, 0, stream>>>(h, parts, 2,
                fin_g, fin_b, (float*)d_out);
    }
}